// Round 17
// baseline (173.919 us; speedup 1.0000x reference)
//
#include <hip/hip_runtime.h>
#include <hip/hip_bf16.h>
#include <stdint.h>

typedef __attribute__((ext_vector_type(8))) short bf16x8;
typedef __attribute__((ext_vector_type(4))) float f32x4;
#define MFMA16 __builtin_amdgcn_mfma_f32_16x16x32_bf16

__device__ __forceinline__ float celu_f(float x) {
    return x > 0.f ? x : 0.1f * (__expf(x * 10.f) - 1.f);
}
__device__ __forceinline__ uint16_t bfb(float x) {
    __hip_bfloat16 h = __float2bfloat16(x);
    return *reinterpret_cast<const uint16_t*>(&h);
}
__device__ __forceinline__ uint32_t pack2(float lo, float hi) {
    return (uint32_t)bfb(lo) | ((uint32_t)bfb(hi) << 16);
}
__device__ __forceinline__ bf16x8 cvt8(float4 a, float4 b) {
    bf16x8 r;
    r[0] = (short)bfb(a.x); r[1] = (short)bfb(a.y); r[2] = (short)bfb(a.z); r[3] = (short)bfb(a.w);
    r[4] = (short)bfb(b.x); r[5] = (short)bfb(b.y); r[6] = (short)bfb(b.z); r[7] = (short)bfb(b.w);
    return r;
}
// async global -> LDS, 16B per lane (dest = uniform base + lane*16)
__device__ __forceinline__ void gload16(const void* g, void* l) {
    __builtin_amdgcn_global_load_lds(
        (const __attribute__((address_space(1))) unsigned int*)g,
        (__attribute__((address_space(3))) unsigned int*)l, 16, 0, 0);
}

// ---------------- pass 0: split+swizzle weights into A-fragment order ----------------
// pair-block (e,mb,kb): 2048 B = [lane l][ hi 16B | lo 16B ]
// A-frag mapping: m = mb*16 + l%16 ; k = kb*32 + (l/16)*8 + j
__device__ __forceinline__ void wsplit_elem(const float* __restrict__ W,
                                            __hip_bfloat16* __restrict__ out,
                                            int idx, int DIN, int DOUT, int MB, int KB) {
    const int PER_E = MB * KB * 512;
    const int e = idx / PER_E;
    int r = idx % PER_E;
    const int mb = r / (KB * 512); r %= KB * 512;
    const int kb = r / 512;        r %= 512;
    const int l = r / 8, j = r % 8;
    const int m = mb * 16 + (l % 16);
    const int k = kb * 32 + (l / 16) * 8 + j;
    const float w = W[((size_t)e * DIN + k) * DOUT + m];
    const __hip_bfloat16 hi = __float2bfloat16(w);
    const float lof = w - __bfloat162float(hi);
    const size_t base = (size_t)(idx / 8) * 16;
    out[base + j]     = hi;
    out[base + 8 + j] = __float2bfloat16(lof);
}

// single dispatch for all three weight tensors; block 0 zeroes counts
// (stream-ordered before bucket; proven R12/R14/R15/R16).
__global__ void prep_kernel(const float* __restrict__ W1, const float* __restrict__ W2,
                            const float* __restrict__ W3,
                            __hip_bfloat16* __restrict__ o1, __hip_bfloat16* __restrict__ o2,
                            __hip_bfloat16* __restrict__ o3, int* counts_zero) {
    if (blockIdx.x == 0 && threadIdx.x < 4) counts_zero[threadIdx.x] = 0;
    const int idx = blockIdx.x * 256 + threadIdx.x;
    constexpr int N1 = 4 * 10 * 12 * 512;   // W1: 245760
    constexpr int N2 = 4 * 8 * 5 * 512;     // W2:  81920
    constexpr int N3 = 4 * 6 * 4 * 512;     // W3:  49152
    if (idx < N1)            wsplit_elem(W1, o1, idx,            384, 160, 10, 12);
    else if (idx < N1 + N2)  wsplit_elem(W2, o2, idx - N1,       160, 128, 8, 5);
    else if (idx < N1 + N2 + N3) wsplit_elem(W3, o3, idx - N1 - N2, 128, 96, 6, 4);
}

// ---------------- pass 1: bucket atoms by species ----------------
__global__ void bucket_kernel(const int* __restrict__ species, int N,
                              int* __restrict__ counts, int* __restrict__ bidx) {
    __shared__ int lcount[4];
    __shared__ int lbase[4];
    const int t = threadIdx.x;
    if (t < 4) lcount[t] = 0;
    __syncthreads();
    const int n = blockIdx.x * blockDim.x + t;
    int sp = 0, lo = 0;
    const bool valid = (n < N);
    if (valid) {
        sp = species[n];
        lo = atomicAdd(&lcount[sp], 1);
    }
    __syncthreads();
    if (t < 4) lbase[t] = atomicAdd(&counts[t], lcount[t]);
    __syncthreads();
    if (valid) bidx[sp * N + lbase[sp] + lo] = n;
}

// ---------------- pass 1b: tile schedule (prefix sum of per-species tile counts) ----
// 128-atom tiles (R8 config).
__global__ void sched_kernel(const int* __restrict__ counts, int* __restrict__ tbase) {
    if (threadIdx.x == 0 && blockIdx.x == 0) {
        int tacc = 0;
        tbase[0] = 0;
        for (int e = 0; e < 4; ++e) { tacc += (counts[e] + 127) >> 7; tbase[e + 1] = tacc; }
    }
}

// ---------------- cooperative weight staging (flat step schedule) ----------------
// steps: L1 = 0..23 (kb=s/2, half=s&1, 5 mb/half), L2 = 24..33 (4 mb/half),
//        L3 = 34..41 (3 mb/half). Unit u = mb_local*2 + (hi/lo), 1KB each.
// 4 waves, u-loop stride 4. Half-kb schedule is the R5/R6/R8/R12/R15/R16-proven one.
// HARD CONSTRAINTS (nondeterministic failures otherwise): no full-kb steps
// (R7/R10), no 512-thread blocks (R11), no wider per-wave tiles (R13),
// no reg-array X pipelines (R3). Register accounting: demand ~84 VGPR + 80
// AGPR (acc) = ~164 unified. (256,3) cap 170 = only 6 slack (no ds_read
// pipelining); (256,4)/128 and (256,5)/102 spill catastrophically.
__device__ __forceinline__ void stage_for(int s, int e, int w, int l,
                                          const char* w1b, const char* w2b,
                                          const char* w3b, char* slot) {
    if (s >= 42) return;
    const int half = s & 1;
    if (s < 24) {
        const int kb = s >> 1;
        for (int u = w; u < 10; u += 4) {
            const int mb = half * 5 + (u >> 1), h = u & 1;
            const char* src = w1b + ((((size_t)e * 10 + mb) * 12 + kb) << 11) + l * 32 + h * 16;
            gload16(src, slot + u * 1024);
        }
    } else if (s < 34) {
        const int kb = (s - 24) >> 1;
        for (int u = w; u < 8; u += 4) {
            const int mb = half * 4 + (u >> 1), h = u & 1;
            const char* src = w2b + ((((size_t)e * 8 + mb) * 5 + kb) << 11) + l * 32 + h * 16;
            gload16(src, slot + u * 1024);
        }
    } else {
        const int kb = (s - 34) >> 1;
        for (int u = w; u < 6; u += 4) {
            const int mb = half * 3 + (u >> 1), h = u & 1;
            const char* src = w3b + ((((size_t)e * 6 + mb) * 4 + kb) << 11) + l * 32 + h * 16;
            gload16(src, slot + u * 1024);
        }
    }
}

// consume MBH mb-units from an LDS slot (contiguous 16B/lane -> conflict-free)
template <int MBH>
__device__ __forceinline__ void consume_slot(const char* slot, int l,
                                             bf16x8 x0, bf16x8 x1, f32x4 (*acc)[2]) {
#pragma unroll
    for (int i = 0; i < MBH; ++i) {
        const bf16x8 whi = *(const bf16x8*)(slot + i * 2048 + l * 16);
        const bf16x8 wlo = *(const bf16x8*)(slot + i * 2048 + 1024 + l * 16);
        acc[i][0] = MFMA16(whi, x0, acc[i][0], 0, 0, 0);
        acc[i][0] = MFMA16(wlo, x0, acc[i][0], 0, 0, 0);
        acc[i][1] = MFMA16(whi, x1, acc[i][1], 0, 0, 0);
        acc[i][1] = MFMA16(wlo, x1, acc[i][1], 0, 0, 0);
    }
}

// ---------------- bias + CELU + pack C-fragments to dwords (in registers) ----------
template <int MB>
__device__ __forceinline__ void pack_epi(const f32x4 (*acc)[2], const float* bb, int q,
                                         uint32_t (*pk)[2][2]) {
    const int fr = q * 4;
#pragma unroll
    for (int mb = 0; mb < MB; ++mb) {
        const float4 bl = *(const float4*)(bb + mb * 16 + fr);
        const float bv[4] = {bl.x, bl.y, bl.z, bl.w};
#pragma unroll
        for (int c = 0; c < 2; ++c) {
            const float o0 = celu_f(acc[mb][c][0] + bv[0]);
            const float o1 = celu_f(acc[mb][c][1] + bv[1]);
            const float o2 = celu_f(acc[mb][c][2] + bv[2]);
            const float o3 = celu_f(acc[mb][c][3] + bv[3]);
            pk[mb][c][0] = pack2(o0, o1);
            pk[mb][c][1] = pack2(o2, o3);
        }
    }
}

// ---------------- in-register C->B transpose across q-groups ----------------
// target lane (a,q), dword d: features 32kb+8q+{2d,2d+1} of its atom.
// source: lane (a, (2q+(d>>1))&3), pk[2kb + (q>=2)][c][d&1].  (verified: R6/R8/R12/R15/R16)
__device__ __forceinline__ bf16x8 xchg(uint32_t pe0, uint32_t pe1,
                                       uint32_t po0, uint32_t po1, int a, int q) {
    union { uint32_t u[4]; bf16x8 v; } r;
#pragma unroll
    for (int d = 0; d < 4; ++d) {
        const int src = a + 16 * ((2 * q + (d >> 1)) & 3);
        const uint32_t ve = __shfl((d & 1) ? pe1 : pe0, src);
        const uint32_t vo = __shfl((d & 1) ? po1 : po0, src);
        r.u[d] = (q >= 2) ? vo : ve;
    }
    return r.v;
}

// ---------------- pass 2: fused MFMA MLP; R16 body, launch_bounds(256,2) ----------
// SINGLE KNOB vs R16: attr (256,3) -> (256,2). Cap 170 -> 256 gives the
// allocator ~90 regs of headroom to pipeline consume-phase ds_read_b128s
// (at cap-170 only 6 slack -> just-in-time reads expose ~120cy LDS latency
// x10/step = the per-step fixed cost). Residency 2.3 -> 2.0 blocks/CU.
// Attr-only changes on this body have never tripped the nondeterminism.
__global__ __launch_bounds__(256, 2) void mlp_mfma_kernel(
    const float* __restrict__ aev, const int* __restrict__ bidx,
    const int* __restrict__ counts, const int* __restrict__ tbase, int N,
    const __hip_bfloat16* __restrict__ wsw1, const float* __restrict__ b1,
    const __hip_bfloat16* __restrict__ wsw2, const float* __restrict__ b2,
    const __hip_bfloat16* __restrict__ wsw3, const float* __restrict__ b3,
    const float* __restrict__ W4, const float* __restrict__ b4,
    float* __restrict__ partials) {
    __shared__ __align__(16) char Wslot[2][10240];
    const int b = blockIdx.x, t = threadIdx.x;
    const int tb1 = tbase[1], tb2 = tbase[2], tb3 = tbase[3], tb4 = tbase[4];
    if (b >= tb4) return;               // block-uniform, before any barrier
    const int e = (b >= tb1) + (b >= tb2) + (b >= tb3);
    const int tile = b - (e == 0 ? 0 : e == 1 ? tb1 : e == 2 ? tb2 : tb3);
    const int cnt = counts[e];
    const int w = t >> 6, l = t & 63;
    const int wbase = tile * 128 + w * 32;
    const int a = l & 15, q = l >> 4;
    const int g0 = wbase + a, g1 = wbase + 16 + a;
    const bool v0g = g0 < cnt, v1g = g1 < cnt;
    // tail waves run masked dummy work on row cnt-1: no wave-level exit.
    const int i0 = bidx[e * N + min(g0, cnt - 1)];
    const int i1 = bidx[e * N + min(g1, cnt - 1)];
    const float* row0 = aev + (size_t)i0 * 384 + q * 8;
    const float* row1 = aev + (size_t)i1 * 384 + q * 8;

    const char* w1b = (const char*)wsw1;
    const char* w2b = (const char*)wsw2;
    const char* w3b = (const char*)wsw3;

    // prologue: stage step 0, preload X kb=0
    float4 na = *(const float4*)(row0);
    float4 nb = *(const float4*)(row0 + 4);
    float4 nc = *(const float4*)(row1);
    float4 nd = *(const float4*)(row1 + 4);
    stage_for(0, e, w, l, w1b, w2b, w3b, &Wslot[0][0]);
    __syncthreads();

    int step = 0;

    // ---- layer 1: X[32x384] -> 160
    f32x4 acc1[10][2] = {};
#pragma unroll 1
    for (int kb = 0; kb < 12; ++kb) {
        const bf16x8 x0 = cvt8(na, nb), x1 = cvt8(nc, nd);
        stage_for(step + 1, e, w, l, w1b, w2b, w3b, &Wslot[(step + 1) & 1][0]);
        consume_slot<5>(&Wslot[step & 1][0], l, x0, x1, &acc1[0]);
        __syncthreads(); ++step;
        if (kb < 11) {                  // named-reg 1-step X prefetch
            na = *(const float4*)(row0 + (kb + 1) * 32);
            nb = *(const float4*)(row0 + (kb + 1) * 32 + 4);
            nc = *(const float4*)(row1 + (kb + 1) * 32);
            nd = *(const float4*)(row1 + (kb + 1) * 32 + 4);
        }
        stage_for(step + 1, e, w, l, w1b, w2b, w3b, &Wslot[(step + 1) & 1][0]);
        consume_slot<5>(&Wslot[step & 1][0], l, x0, x1, &acc1[5]);
        __syncthreads(); ++step;
    }

    // ---- layer 1 -> 2 interface: pack + shuffle transpose (no LDS)
    uint32_t pk1[10][2][2];
    pack_epi<10>(acc1, b1 + e * 160, q, pk1);

    // ---- layer 2: 160 -> 128 (steps 24..33, fully unrolled: static pk indices)
    f32x4 acc2[8][2] = {};
#pragma unroll
    for (int kb2 = 0; kb2 < 5; ++kb2) {
        const bf16x8 h0 = xchg(pk1[2 * kb2][0][0], pk1[2 * kb2][0][1],
                               pk1[2 * kb2 + 1][0][0], pk1[2 * kb2 + 1][0][1], a, q);
        const bf16x8 h1 = xchg(pk1[2 * kb2][1][0], pk1[2 * kb2][1][1],
                               pk1[2 * kb2 + 1][1][0], pk1[2 * kb2 + 1][1][1], a, q);
        const int s0 = 24 + 2 * kb2;
        stage_for(s0 + 1, e, w, l, w1b, w2b, w3b, &Wslot[(s0 + 1) & 1][0]);
        consume_slot<4>(&Wslot[s0 & 1][0], l, h0, h1, &acc2[0]);
        __syncthreads();
        stage_for(s0 + 2, e, w, l, w1b, w2b, w3b, &Wslot[(s0 + 2) & 1][0]);
        consume_slot<4>(&Wslot[(s0 + 1) & 1][0], l, h0, h1, &acc2[4]);
        __syncthreads();
    }

    // ---- layer 2 -> 3 interface
    uint32_t pk2[8][2][2];
    pack_epi<8>(acc2, b2 + e * 128, q, pk2);

    // ---- layer 3: 128 -> 96 (steps 34..41, fully unrolled)
    f32x4 acc3[6][2] = {};
#pragma unroll
    for (int kb3 = 0; kb3 < 4; ++kb3) {
        const bf16x8 h0 = xchg(pk2[2 * kb3][0][0], pk2[2 * kb3][0][1],
                               pk2[2 * kb3 + 1][0][0], pk2[2 * kb3 + 1][0][1], a, q);
        const bf16x8 h1 = xchg(pk2[2 * kb3][1][0], pk2[2 * kb3][1][1],
                               pk2[2 * kb3 + 1][1][0], pk2[2 * kb3 + 1][1][1], a, q);
        const int s0 = 34 + 2 * kb3;
        stage_for(s0 + 1, e, w, l, w1b, w2b, w3b, &Wslot[(s0 + 1) & 1][0]);
        consume_slot<3>(&Wslot[s0 & 1][0], l, h0, h1, &acc3[0]);
        __syncthreads();
        stage_for(s0 + 2, e, w, l, w1b, w2b, w3b, &Wslot[(s0 + 2) & 1][0]);  // 42 = no-op at end
        consume_slot<3>(&Wslot[(s0 + 1) & 1][0], l, h0, h1, &acc3[3]);
        __syncthreads();
    }

    // ---- layer 3 epilogue fused with layer 4 (96 -> 1) dot
    const int fr = q * 4;
    float en0 = 0.f, en1 = 0.f;
#pragma unroll
    for (int mb = 0; mb < 6; ++mb) {
        const float4 bl = *(const float4*)(b3 + e * 96 + mb * 16 + fr);
        const float4 wv = *(const float4*)(W4 + e * 96 + mb * 16 + fr);
        const float bv[4] = {bl.x, bl.y, bl.z, bl.w};
        const float wb[4] = {wv.x, wv.y, wv.z, wv.w};
#pragma unroll
        for (int r = 0; r < 4; ++r) {
            en0 += celu_f(acc3[mb][0][r] + bv[r]) * wb[r];
            en1 += celu_f(acc3[mb][1][r] + bv[r]) * wb[r];
        }
    }
    en0 += __shfl_xor(en0, 16); en0 += __shfl_xor(en0, 32);
    en1 += __shfl_xor(en1, 16); en1 += __shfl_xor(en1, 32);
    const float b4e = b4[e];
    float p = 0.f;
    if (l < 16) p = (v0g ? en0 + b4e : 0.f) + (v1g ? en1 + b4e : 0.f);
#pragma unroll
    for (int off = 1; off <= 32; off <<= 1) p += __shfl_xor(p, off);
    if (l == 0) partials[b * 4 + w] = p;
}

// ---------------- pass 3: deterministic tree reduce (1024 threads, 16 waves) -----
__global__ void reduce_kernel(const float* __restrict__ partials,
                              const int* __restrict__ tbase, float* __restrict__ out) {
    __shared__ float wsum[16];
    const int n = tbase[4] * 4;
    const int t = threadIdx.x;
    float s = 0.f;
    for (int i = t; i < n; i += 1024) s += partials[i];
#pragma unroll
    for (int off = 32; off; off >>= 1) s += __shfl_down(s, off);
    if ((t & 63) == 0) wsum[t >> 6] = s;
    __syncthreads();
    if (t == 0) {
        float tot = 0.f;
        for (int ww = 0; ww < 16; ++ww) tot += wsum[ww];
        out[0] = tot;
    }
}

extern "C" void kernel_launch(void* const* d_in, const int* in_sizes, int n_in,
                              void* d_out, int out_size, void* d_ws, size_t ws_size,
                              hipStream_t stream) {
    const float* aev     = (const float*)d_in[0];
    const int*   species = (const int*)d_in[1];
    const float* W1 = (const float*)d_in[2];
    const float* b1 = (const float*)d_in[3];
    const float* W2 = (const float*)d_in[4];
    const float* b2 = (const float*)d_in[5];
    const float* W3 = (const float*)d_in[6];
    const float* b3 = (const float*)d_in[7];
    const float* W4 = (const float*)d_in[8];
    const float* b4 = (const float*)d_in[9];
    float* out = (float*)d_out;

    const int N = in_sizes[1];
    const int gridx_max = (N + 127) / 128 + 4;   // >= sum_e ceil(cnt_e/128)

    // ws layout (256-aligned regions): counts[4] @0, tbase[5] @16, partials @256
    char* ws = (char*)d_ws;
    int* counts = (int*)ws;
    int* tbase  = (int*)(ws + 16);
    float* partials = (float*)(ws + 256);
    size_t off = 256 + (size_t)gridx_max * 4 * sizeof(float);
    off = (off + 255) & ~(size_t)255;
    __hip_bfloat16* wsw1 = (__hip_bfloat16*)(ws + off); off += (size_t)4 * 384 * 160 * 2 * 2;
    __hip_bfloat16* wsw2 = (__hip_bfloat16*)(ws + off); off += (size_t)4 * 160 * 128 * 2 * 2;
    __hip_bfloat16* wsw3 = (__hip_bfloat16*)(ws + off); off += (size_t)4 * 128 * 96 * 2 * 2;
    int* bidx = (int*)(ws + off);

    // single prep dispatch: all 3 weight splits + counts zeroing.
    constexpr int PREP_TOTAL = 4 * (10 * 12 + 8 * 5 + 6 * 4) * 512;   // 376832
    prep_kernel<<<(PREP_TOTAL + 255) / 256, 256, 0, stream>>>(W1, W2, W3,
                                                              wsw1, wsw2, wsw3, counts);

    bucket_kernel<<<(N + 255) / 256, 256, 0, stream>>>(species, N, counts, bidx);
    sched_kernel<<<1, 64, 0, stream>>>(counts, tbase);

    mlp_mfma_kernel<<<gridx_max, 256, 0, stream>>>(aev, bidx, counts, tbase, N,
                                                   wsw1, b1, wsw2, b2, wsw3, b3, W4, b4,
                                                   partials);

    reduce_kernel<<<1, 1024, 0, stream>>>(partials, tbase, out);
}

// Round 18
// 163.607 us; speedup vs baseline: 1.0630x; 1.0630x over previous
//
#include <hip/hip_runtime.h>
#include <hip/hip_bf16.h>
#include <stdint.h>

typedef __attribute__((ext_vector_type(8))) short bf16x8;
typedef __attribute__((ext_vector_type(4))) float f32x4;
#define MFMA16 __builtin_amdgcn_mfma_f32_16x16x32_bf16

__device__ __forceinline__ float celu_f(float x) {
    return x > 0.f ? x : 0.1f * (__expf(x * 10.f) - 1.f);
}
__device__ __forceinline__ uint16_t bfb(float x) {
    __hip_bfloat16 h = __float2bfloat16(x);
    return *reinterpret_cast<const uint16_t*>(&h);
}
__device__ __forceinline__ uint32_t pack2(float lo, float hi) {
    return (uint32_t)bfb(lo) | ((uint32_t)bfb(hi) << 16);
}
__device__ __forceinline__ bf16x8 cvt8(float4 a, float4 b) {
    bf16x8 r;
    r[0] = (short)bfb(a.x); r[1] = (short)bfb(a.y); r[2] = (short)bfb(a.z); r[3] = (short)bfb(a.w);
    r[4] = (short)bfb(b.x); r[5] = (short)bfb(b.y); r[6] = (short)bfb(b.z); r[7] = (short)bfb(b.w);
    return r;
}
// async global -> LDS, 16B per lane (dest = uniform base + lane*16)
__device__ __forceinline__ void gload16(const void* g, void* l) {
    __builtin_amdgcn_global_load_lds(
        (const __attribute__((address_space(1))) unsigned int*)g,
        (__attribute__((address_space(3))) unsigned int*)l, 16, 0, 0);
}

// ---------------- pass 0: split+swizzle weights into A-fragment order ----------------
// pair-block (e,mb,kb): 2048 B = [lane l][ hi 16B | lo 16B ]
// A-frag mapping: m = mb*16 + l%16 ; k = kb*32 + (l/16)*8 + j
__device__ __forceinline__ void wsplit_elem(const float* __restrict__ W,
                                            __hip_bfloat16* __restrict__ out,
                                            int idx, int DIN, int DOUT, int MB, int KB) {
    const int PER_E = MB * KB * 512;
    const int e = idx / PER_E;
    int r = idx % PER_E;
    const int mb = r / (KB * 512); r %= KB * 512;
    const int kb = r / 512;        r %= 512;
    const int l = r / 8, j = r % 8;
    const int m = mb * 16 + (l % 16);
    const int k = kb * 32 + (l / 16) * 8 + j;
    const float w = W[((size_t)e * DIN + k) * DOUT + m];
    const __hip_bfloat16 hi = __float2bfloat16(w);
    const float lof = w - __bfloat162float(hi);
    const size_t base = (size_t)(idx / 8) * 16;
    out[base + j]     = hi;
    out[base + 8 + j] = __float2bfloat16(lof);
}

// single dispatch for all three weight tensors; block 0 zeroes counts
// (stream-ordered before bucket; proven R12/R14/R15/R16).
__global__ void prep_kernel(const float* __restrict__ W1, const float* __restrict__ W2,
                            const float* __restrict__ W3,
                            __hip_bfloat16* __restrict__ o1, __hip_bfloat16* __restrict__ o2,
                            __hip_bfloat16* __restrict__ o3, int* counts_zero) {
    if (blockIdx.x == 0 && threadIdx.x < 4) counts_zero[threadIdx.x] = 0;
    const int idx = blockIdx.x * 256 + threadIdx.x;
    constexpr int N1 = 4 * 10 * 12 * 512;   // W1: 245760
    constexpr int N2 = 4 * 8 * 5 * 512;     // W2:  81920
    constexpr int N3 = 4 * 6 * 4 * 512;     // W3:  49152
    if (idx < N1)            wsplit_elem(W1, o1, idx,            384, 160, 10, 12);
    else if (idx < N1 + N2)  wsplit_elem(W2, o2, idx - N1,       160, 128, 8, 5);
    else if (idx < N1 + N2 + N3) wsplit_elem(W3, o3, idx - N1 - N2, 128, 96, 6, 4);
}

// ---------------- pass 1: bucket atoms by species ----------------
__global__ void bucket_kernel(const int* __restrict__ species, int N,
                              int* __restrict__ counts, int* __restrict__ bidx) {
    __shared__ int lcount[4];
    __shared__ int lbase[4];
    const int t = threadIdx.x;
    if (t < 4) lcount[t] = 0;
    __syncthreads();
    const int n = blockIdx.x * blockDim.x + t;
    int sp = 0, lo = 0;
    const bool valid = (n < N);
    if (valid) {
        sp = species[n];
        lo = atomicAdd(&lcount[sp], 1);
    }
    __syncthreads();
    if (t < 4) lbase[t] = atomicAdd(&counts[t], lcount[t]);
    __syncthreads();
    if (valid) bidx[sp * N + lbase[sp] + lo] = n;
}

// ---------------- pass 1b: tile schedule (prefix sum of per-species tile counts) ----
// 128-atom tiles (R8 config).
__global__ void sched_kernel(const int* __restrict__ counts, int* __restrict__ tbase) {
    if (threadIdx.x == 0 && blockIdx.x == 0) {
        int tacc = 0;
        tbase[0] = 0;
        for (int e = 0; e < 4; ++e) { tacc += (counts[e] + 127) >> 7; tbase[e + 1] = tacc; }
    }
}

// ---------------- cooperative weight staging (flat step schedule) ----------------
// steps: L1 = 0..23 (kb=s/2, half=s&1, 5 mb/half), L2 = 24..33 (4 mb/half),
//        L3 = 34..41 (3 mb/half). Unit u = mb_local*2 + (hi/lo), 1KB each.
// 4 waves, u-loop stride 4. Half-kb schedule is the R5/R6/R8/R12/R15/R16-proven one.
// HARD CONSTRAINTS (nondeterministic failures otherwise): no full-kb steps
// (R7/R10), no 512-thread blocks (R11), no wider per-wave tiles (R13),
// no reg-array X pipelines (R3). launch_bounds: ONLY (256,3) — cap<170
// spills (R6/R9/R14); cap>170 loses occupancy for no schedule gain (R17:
// (256,2) -> VGPR 96, occ 20, +10us). Register accounting: ~84 VGPR + 80
// AGPR (acc) = ~164 unified vs cap 170.
__device__ __forceinline__ void stage_for(int s, int e, int w, int l,
                                          const char* w1b, const char* w2b,
                                          const char* w3b, char* slot) {
    if (s >= 42) return;
    const int half = s & 1;
    if (s < 24) {
        const int kb = s >> 1;
        for (int u = w; u < 10; u += 4) {
            const int mb = half * 5 + (u >> 1), h = u & 1;
            const char* src = w1b + ((((size_t)e * 10 + mb) * 12 + kb) << 11) + l * 32 + h * 16;
            gload16(src, slot + u * 1024);
        }
    } else if (s < 34) {
        const int kb = (s - 24) >> 1;
        for (int u = w; u < 8; u += 4) {
            const int mb = half * 4 + (u >> 1), h = u & 1;
            const char* src = w2b + ((((size_t)e * 8 + mb) * 5 + kb) << 11) + l * 32 + h * 16;
            gload16(src, slot + u * 1024);
        }
    } else {
        const int kb = (s - 34) >> 1;
        for (int u = w; u < 6; u += 4) {
            const int mb = half * 3 + (u >> 1), h = u & 1;
            const char* src = w3b + ((((size_t)e * 6 + mb) * 4 + kb) << 11) + l * 32 + h * 16;
            gload16(src, slot + u * 1024);
        }
    }
}

// consume MBH mb-units from an LDS slot (contiguous 16B/lane -> conflict-free)
template <int MBH>
__device__ __forceinline__ void consume_slot(const char* slot, int l,
                                             bf16x8 x0, bf16x8 x1, f32x4 (*acc)[2]) {
#pragma unroll
    for (int i = 0; i < MBH; ++i) {
        const bf16x8 whi = *(const bf16x8*)(slot + i * 2048 + l * 16);
        const bf16x8 wlo = *(const bf16x8*)(slot + i * 2048 + 1024 + l * 16);
        acc[i][0] = MFMA16(whi, x0, acc[i][0], 0, 0, 0);
        acc[i][0] = MFMA16(wlo, x0, acc[i][0], 0, 0, 0);
        acc[i][1] = MFMA16(whi, x1, acc[i][1], 0, 0, 0);
        acc[i][1] = MFMA16(wlo, x1, acc[i][1], 0, 0, 0);
    }
}

// ---------------- bias + CELU + pack C-fragments to dwords (in registers) ----------
template <int MB>
__device__ __forceinline__ void pack_epi(const f32x4 (*acc)[2], const float* bb, int q,
                                         uint32_t (*pk)[2][2]) {
    const int fr = q * 4;
#pragma unroll
    for (int mb = 0; mb < MB; ++mb) {
        const float4 bl = *(const float4*)(bb + mb * 16 + fr);
        const float bv[4] = {bl.x, bl.y, bl.z, bl.w};
#pragma unroll
        for (int c = 0; c < 2; ++c) {
            const float o0 = celu_f(acc[mb][c][0] + bv[0]);
            const float o1 = celu_f(acc[mb][c][1] + bv[1]);
            const float o2 = celu_f(acc[mb][c][2] + bv[2]);
            const float o3 = celu_f(acc[mb][c][3] + bv[3]);
            pk[mb][c][0] = pack2(o0, o1);
            pk[mb][c][1] = pack2(o2, o3);
        }
    }
}

// ---------------- in-register C->B transpose across q-groups ----------------
// target lane (a,q), dword d: features 32kb+8q+{2d,2d+1} of its atom.
// source: lane (a, (2q+(d>>1))&3), pk[2kb + (q>=2)][c][d&1].  (verified: R6/R8/R12/R15/R16)
__device__ __forceinline__ bf16x8 xchg(uint32_t pe0, uint32_t pe1,
                                       uint32_t po0, uint32_t po1, int a, int q) {
    union { uint32_t u[4]; bf16x8 v; } r;
#pragma unroll
    for (int d = 0; d < 4; ++d) {
        const int src = a + 16 * ((2 * q + (d >> 1)) & 3);
        const uint32_t ve = __shfl((d & 1) ? pe1 : pe0, src);
        const uint32_t vo = __shfl((d & 1) ? po1 : po0, src);
        r.u[d] = (q >= 2) ? vo : ve;
    }
    return r.v;
}

// ---------------- pass 2: fused MFMA MLP; the R16-verified optimum ----------
// 4 waves x 32 atoms = 128-atom tiles; half-kb 42-step staging; __syncthreads
// steps; __launch_bounds__(256,3) -> VGPR 84 (at cap, no spill), 20.5KB LDS,
// ~2.3 blocks/CU. Verified best: 163.5us total (R16). BODY FROZEN.
__global__ __launch_bounds__(256, 3) void mlp_mfma_kernel(
    const float* __restrict__ aev, const int* __restrict__ bidx,
    const int* __restrict__ counts, const int* __restrict__ tbase, int N,
    const __hip_bfloat16* __restrict__ wsw1, const float* __restrict__ b1,
    const __hip_bfloat16* __restrict__ wsw2, const float* __restrict__ b2,
    const __hip_bfloat16* __restrict__ wsw3, const float* __restrict__ b3,
    const float* __restrict__ W4, const float* __restrict__ b4,
    float* __restrict__ partials) {
    __shared__ __align__(16) char Wslot[2][10240];
    const int b = blockIdx.x, t = threadIdx.x;
    const int tb1 = tbase[1], tb2 = tbase[2], tb3 = tbase[3], tb4 = tbase[4];
    if (b >= tb4) return;               // block-uniform, before any barrier
    const int e = (b >= tb1) + (b >= tb2) + (b >= tb3);
    const int tile = b - (e == 0 ? 0 : e == 1 ? tb1 : e == 2 ? tb2 : tb3);
    const int cnt = counts[e];
    const int w = t >> 6, l = t & 63;
    const int wbase = tile * 128 + w * 32;
    const int a = l & 15, q = l >> 4;
    const int g0 = wbase + a, g1 = wbase + 16 + a;
    const bool v0g = g0 < cnt, v1g = g1 < cnt;
    // tail waves run masked dummy work on row cnt-1: no wave-level exit.
    const int i0 = bidx[e * N + min(g0, cnt - 1)];
    const int i1 = bidx[e * N + min(g1, cnt - 1)];
    const float* row0 = aev + (size_t)i0 * 384 + q * 8;
    const float* row1 = aev + (size_t)i1 * 384 + q * 8;

    const char* w1b = (const char*)wsw1;
    const char* w2b = (const char*)wsw2;
    const char* w3b = (const char*)wsw3;

    // prologue: stage step 0, preload X kb=0
    float4 na = *(const float4*)(row0);
    float4 nb = *(const float4*)(row0 + 4);
    float4 nc = *(const float4*)(row1);
    float4 nd = *(const float4*)(row1 + 4);
    stage_for(0, e, w, l, w1b, w2b, w3b, &Wslot[0][0]);
    __syncthreads();

    int step = 0;

    // ---- layer 1: X[32x384] -> 160
    f32x4 acc1[10][2] = {};
#pragma unroll 1
    for (int kb = 0; kb < 12; ++kb) {
        const bf16x8 x0 = cvt8(na, nb), x1 = cvt8(nc, nd);
        stage_for(step + 1, e, w, l, w1b, w2b, w3b, &Wslot[(step + 1) & 1][0]);
        consume_slot<5>(&Wslot[step & 1][0], l, x0, x1, &acc1[0]);
        __syncthreads(); ++step;
        if (kb < 11) {                  // named-reg 1-step X prefetch
            na = *(const float4*)(row0 + (kb + 1) * 32);
            nb = *(const float4*)(row0 + (kb + 1) * 32 + 4);
            nc = *(const float4*)(row1 + (kb + 1) * 32);
            nd = *(const float4*)(row1 + (kb + 1) * 32 + 4);
        }
        stage_for(step + 1, e, w, l, w1b, w2b, w3b, &Wslot[(step + 1) & 1][0]);
        consume_slot<5>(&Wslot[step & 1][0], l, x0, x1, &acc1[5]);
        __syncthreads(); ++step;
    }

    // ---- layer 1 -> 2 interface: pack + shuffle transpose (no LDS)
    uint32_t pk1[10][2][2];
    pack_epi<10>(acc1, b1 + e * 160, q, pk1);

    // ---- layer 2: 160 -> 128 (steps 24..33, fully unrolled: static pk indices)
    f32x4 acc2[8][2] = {};
#pragma unroll
    for (int kb2 = 0; kb2 < 5; ++kb2) {
        const bf16x8 h0 = xchg(pk1[2 * kb2][0][0], pk1[2 * kb2][0][1],
                               pk1[2 * kb2 + 1][0][0], pk1[2 * kb2 + 1][0][1], a, q);
        const bf16x8 h1 = xchg(pk1[2 * kb2][1][0], pk1[2 * kb2][1][1],
                               pk1[2 * kb2 + 1][1][0], pk1[2 * kb2 + 1][1][1], a, q);
        const int s0 = 24 + 2 * kb2;
        stage_for(s0 + 1, e, w, l, w1b, w2b, w3b, &Wslot[(s0 + 1) & 1][0]);
        consume_slot<4>(&Wslot[s0 & 1][0], l, h0, h1, &acc2[0]);
        __syncthreads();
        stage_for(s0 + 2, e, w, l, w1b, w2b, w3b, &Wslot[(s0 + 2) & 1][0]);
        consume_slot<4>(&Wslot[(s0 + 1) & 1][0], l, h0, h1, &acc2[4]);
        __syncthreads();
    }

    // ---- layer 2 -> 3 interface
    uint32_t pk2[8][2][2];
    pack_epi<8>(acc2, b2 + e * 128, q, pk2);

    // ---- layer 3: 128 -> 96 (steps 34..41, fully unrolled)
    f32x4 acc3[6][2] = {};
#pragma unroll
    for (int kb3 = 0; kb3 < 4; ++kb3) {
        const bf16x8 h0 = xchg(pk2[2 * kb3][0][0], pk2[2 * kb3][0][1],
                               pk2[2 * kb3 + 1][0][0], pk2[2 * kb3 + 1][0][1], a, q);
        const bf16x8 h1 = xchg(pk2[2 * kb3][1][0], pk2[2 * kb3][1][1],
                               pk2[2 * kb3 + 1][1][0], pk2[2 * kb3 + 1][1][1], a, q);
        const int s0 = 34 + 2 * kb3;
        stage_for(s0 + 1, e, w, l, w1b, w2b, w3b, &Wslot[(s0 + 1) & 1][0]);
        consume_slot<3>(&Wslot[s0 & 1][0], l, h0, h1, &acc3[0]);
        __syncthreads();
        stage_for(s0 + 2, e, w, l, w1b, w2b, w3b, &Wslot[(s0 + 2) & 1][0]);  // 42 = no-op at end
        consume_slot<3>(&Wslot[(s0 + 1) & 1][0], l, h0, h1, &acc3[3]);
        __syncthreads();
    }

    // ---- layer 3 epilogue fused with layer 4 (96 -> 1) dot
    const int fr = q * 4;
    float en0 = 0.f, en1 = 0.f;
#pragma unroll
    for (int mb = 0; mb < 6; ++mb) {
        const float4 bl = *(const float4*)(b3 + e * 96 + mb * 16 + fr);
        const float4 wv = *(const float4*)(W4 + e * 96 + mb * 16 + fr);
        const float bv[4] = {bl.x, bl.y, bl.z, bl.w};
        const float wb[4] = {wv.x, wv.y, wv.z, wv.w};
#pragma unroll
        for (int r = 0; r < 4; ++r) {
            en0 += celu_f(acc3[mb][0][r] + bv[r]) * wb[r];
            en1 += celu_f(acc3[mb][1][r] + bv[r]) * wb[r];
        }
    }
    en0 += __shfl_xor(en0, 16); en0 += __shfl_xor(en0, 32);
    en1 += __shfl_xor(en1, 16); en1 += __shfl_xor(en1, 32);
    const float b4e = b4[e];
    float p = 0.f;
    if (l < 16) p = (v0g ? en0 + b4e : 0.f) + (v1g ? en1 + b4e : 0.f);
#pragma unroll
    for (int off = 1; off <= 32; off <<= 1) p += __shfl_xor(p, off);
    if (l == 0) partials[b * 4 + w] = p;
}

// ---------------- pass 3: deterministic tree reduce (1024 threads, 16 waves) -----
__global__ void reduce_kernel(const float* __restrict__ partials,
                              const int* __restrict__ tbase, float* __restrict__ out) {
    __shared__ float wsum[16];
    const int n = tbase[4] * 4;
    const int t = threadIdx.x;
    float s = 0.f;
    for (int i = t; i < n; i += 1024) s += partials[i];
#pragma unroll
    for (int off = 32; off; off >>= 1) s += __shfl_down(s, off);
    if ((t & 63) == 0) wsum[t >> 6] = s;
    __syncthreads();
    if (t == 0) {
        float tot = 0.f;
        for (int ww = 0; ww < 16; ++ww) tot += wsum[ww];
        out[0] = tot;
    }
}

extern "C" void kernel_launch(void* const* d_in, const int* in_sizes, int n_in,
                              void* d_out, int out_size, void* d_ws, size_t ws_size,
                              hipStream_t stream) {
    const float* aev     = (const float*)d_in[0];
    const int*   species = (const int*)d_in[1];
    const float* W1 = (const float*)d_in[2];
    const float* b1 = (const float*)d_in[3];
    const float* W2 = (const float*)d_in[4];
    const float* b2 = (const float*)d_in[5];
    const float* W3 = (const float*)d_in[6];
    const float* b3 = (const float*)d_in[7];
    const float* W4 = (const float*)d_in[8];
    const float* b4 = (const float*)d_in[9];
    float* out = (float*)d_out;

    const int N = in_sizes[1];
    const int gridx_max = (N + 127) / 128 + 4;   // >= sum_e ceil(cnt_e/128)

    // ws layout (256-aligned regions): counts[4] @0, tbase[5] @16, partials @256
    char* ws = (char*)d_ws;
    int* counts = (int*)ws;
    int* tbase  = (int*)(ws + 16);
    float* partials = (float*)(ws + 256);
    size_t off = 256 + (size_t)gridx_max * 4 * sizeof(float);
    off = (off + 255) & ~(size_t)255;
    __hip_bfloat16* wsw1 = (__hip_bfloat16*)(ws + off); off += (size_t)4 * 384 * 160 * 2 * 2;
    __hip_bfloat16* wsw2 = (__hip_bfloat16*)(ws + off); off += (size_t)4 * 160 * 128 * 2 * 2;
    __hip_bfloat16* wsw3 = (__hip_bfloat16*)(ws + off); off += (size_t)4 * 128 * 96 * 2 * 2;
    int* bidx = (int*)(ws + off);

    // single prep dispatch: all 3 weight splits + counts zeroing.
    constexpr int PREP_TOTAL = 4 * (10 * 12 + 8 * 5 + 6 * 4) * 512;   // 376832
    prep_kernel<<<(PREP_TOTAL + 255) / 256, 256, 0, stream>>>(W1, W2, W3,
                                                              wsw1, wsw2, wsw3, counts);

    bucket_kernel<<<(N + 255) / 256, 256, 0, stream>>>(species, N, counts, bidx);
    sched_kernel<<<1, 64, 0, stream>>>(counts, tbase);

    mlp_mfma_kernel<<<gridx_max, 256, 0, stream>>>(aev, bidx, counts, tbase, N,
                                                   wsw1, b1, wsw2, b2, wsw3, b3, W4, b4,
                                                   partials);

    reduce_kernel<<<1, 1024, 0, stream>>>(partials, tbase, out);
}

// Round 19
// 163.360 us; speedup vs baseline: 1.0646x; 1.0015x over previous
//
#include <hip/hip_runtime.h>
#include <hip/hip_bf16.h>
#include <stdint.h>

typedef __attribute__((ext_vector_type(8))) short bf16x8;
typedef __attribute__((ext_vector_type(4))) float f32x4;
#define MFMA16 __builtin_amdgcn_mfma_f32_16x16x32_bf16

__device__ __forceinline__ float celu_f(float x) {
    return x > 0.f ? x : 0.1f * (__expf(x * 10.f) - 1.f);
}
__device__ __forceinline__ uint16_t bfb(float x) {
    __hip_bfloat16 h = __float2bfloat16(x);
    return *reinterpret_cast<const uint16_t*>(&h);
}
__device__ __forceinline__ uint32_t pack2(float lo, float hi) {
    return (uint32_t)bfb(lo) | ((uint32_t)bfb(hi) << 16);
}
__device__ __forceinline__ bf16x8 cvt8(float4 a, float4 b) {
    bf16x8 r;
    r[0] = (short)bfb(a.x); r[1] = (short)bfb(a.y); r[2] = (short)bfb(a.z); r[3] = (short)bfb(a.w);
    r[4] = (short)bfb(b.x); r[5] = (short)bfb(b.y); r[6] = (short)bfb(b.z); r[7] = (short)bfb(b.w);
    return r;
}
// async global -> LDS, 16B per lane (dest = uniform base + lane*16)
__device__ __forceinline__ void gload16(const void* g, void* l) {
    __builtin_amdgcn_global_load_lds(
        (const __attribute__((address_space(1))) unsigned int*)g,
        (__attribute__((address_space(3))) unsigned int*)l, 16, 0, 0);
}

// ---------------- pass 0: split+swizzle weights into A-fragment order ----------------
// pair-block (e,mb,kb): 2048 B = [lane l][ hi 16B | lo 16B ]
// A-frag mapping: m = mb*16 + l%16 ; k = kb*32 + (l/16)*8 + j
__device__ __forceinline__ void wsplit_elem(const float* __restrict__ W,
                                            __hip_bfloat16* __restrict__ out,
                                            int idx, int DIN, int DOUT, int MB, int KB) {
    const int PER_E = MB * KB * 512;
    const int e = idx / PER_E;
    int r = idx % PER_E;
    const int mb = r / (KB * 512); r %= KB * 512;
    const int kb = r / 512;        r %= 512;
    const int l = r / 8, j = r % 8;
    const int m = mb * 16 + (l % 16);
    const int k = kb * 32 + (l / 16) * 8 + j;
    const float w = W[((size_t)e * DIN + k) * DOUT + m];
    const __hip_bfloat16 hi = __float2bfloat16(w);
    const float lof = w - __bfloat162float(hi);
    const size_t base = (size_t)(idx / 8) * 16;
    out[base + j]     = hi;
    out[base + 8 + j] = __float2bfloat16(lof);
}

// single dispatch for all three weight tensors; block 0 zeroes counts
// (stream-ordered before bucket; proven R12/R14/R15/R16/R18).
__global__ void prep_kernel(const float* __restrict__ W1, const float* __restrict__ W2,
                            const float* __restrict__ W3,
                            __hip_bfloat16* __restrict__ o1, __hip_bfloat16* __restrict__ o2,
                            __hip_bfloat16* __restrict__ o3, int* counts_zero) {
    if (blockIdx.x == 0 && threadIdx.x < 4) counts_zero[threadIdx.x] = 0;
    const int idx = blockIdx.x * 256 + threadIdx.x;
    constexpr int N1 = 4 * 10 * 12 * 512;   // W1: 245760
    constexpr int N2 = 4 * 8 * 5 * 512;     // W2:  81920
    constexpr int N3 = 4 * 6 * 4 * 512;     // W3:  49152
    if (idx < N1)            wsplit_elem(W1, o1, idx,            384, 160, 10, 12);
    else if (idx < N1 + N2)  wsplit_elem(W2, o2, idx - N1,       160, 128, 8, 5);
    else if (idx < N1 + N2 + N3) wsplit_elem(W3, o3, idx - N1 - N2, 128, 96, 6, 4);
}

// ---------------- pass 1: bucket atoms by species ----------------
__global__ void bucket_kernel(const int* __restrict__ species, int N,
                              int* __restrict__ counts, int* __restrict__ bidx) {
    __shared__ int lcount[4];
    __shared__ int lbase[4];
    const int t = threadIdx.x;
    if (t < 4) lcount[t] = 0;
    __syncthreads();
    const int n = blockIdx.x * blockDim.x + t;
    int sp = 0, lo = 0;
    const bool valid = (n < N);
    if (valid) {
        sp = species[n];
        lo = atomicAdd(&lcount[sp], 1);
    }
    __syncthreads();
    if (t < 4) lbase[t] = atomicAdd(&counts[t], lcount[t]);
    __syncthreads();
    if (valid) bidx[sp * N + lbase[sp] + lo] = n;
}

// ---------------- pass 1b: tile schedule (prefix sum of per-species tile counts) ----
// 128-atom tiles (R8 config).
__global__ void sched_kernel(const int* __restrict__ counts, int* __restrict__ tbase) {
    if (threadIdx.x == 0 && blockIdx.x == 0) {
        int tacc = 0;
        tbase[0] = 0;
        for (int e = 0; e < 4; ++e) { tacc += (counts[e] + 127) >> 7; tbase[e + 1] = tacc; }
    }
}

// ---------------- cooperative weight staging (flat step schedule) ----------------
// steps: L1 = 0..23 (kb=s/2, half=s&1, 5 mb/half), L2 = 24..33 (4 mb/half),
//        L3 = 34..41 (3 mb/half). Unit u = mb_local*2 + (hi/lo), 1KB each.
// 4 waves, u-loop stride 4. Half-kb schedule is the R5/R6/R8/R12/R15/R16/R18-proven one.
// HARD CONSTRAINTS (nondeterministic failures otherwise): no full-kb steps
// (R7/R10), no 512-thread blocks (R11), no wider per-wave tiles (R13),
// no reg-array X pipelines (R3). launch_bounds: ONLY (256,3) — cap<170
// spills (R6/R9/R14); cap>170 loses occupancy for no schedule gain (R17).
// Register accounting: ~84 VGPR + 80 AGPR (acc) = ~164 unified vs cap 170.
__device__ __forceinline__ void stage_for(int s, int e, int w, int l,
                                          const char* w1b, const char* w2b,
                                          const char* w3b, char* slot) {
    if (s >= 42) return;
    const int half = s & 1;
    if (s < 24) {
        const int kb = s >> 1;
        for (int u = w; u < 10; u += 4) {
            const int mb = half * 5 + (u >> 1), h = u & 1;
            const char* src = w1b + ((((size_t)e * 10 + mb) * 12 + kb) << 11) + l * 32 + h * 16;
            gload16(src, slot + u * 1024);
        }
    } else if (s < 34) {
        const int kb = (s - 24) >> 1;
        for (int u = w; u < 8; u += 4) {
            const int mb = half * 4 + (u >> 1), h = u & 1;
            const char* src = w2b + ((((size_t)e * 8 + mb) * 5 + kb) << 11) + l * 32 + h * 16;
            gload16(src, slot + u * 1024);
        }
    } else {
        const int kb = (s - 34) >> 1;
        for (int u = w; u < 6; u += 4) {
            const int mb = half * 3 + (u >> 1), h = u & 1;
            const char* src = w3b + ((((size_t)e * 6 + mb) * 4 + kb) << 11) + l * 32 + h * 16;
            gload16(src, slot + u * 1024);
        }
    }
}

// consume MBH mb-units from an LDS slot (contiguous 16B/lane -> conflict-free)
template <int MBH>
__device__ __forceinline__ void consume_slot(const char* slot, int l,
                                             bf16x8 x0, bf16x8 x1, f32x4 (*acc)[2]) {
#pragma unroll
    for (int i = 0; i < MBH; ++i) {
        const bf16x8 whi = *(const bf16x8*)(slot + i * 2048 + l * 16);
        const bf16x8 wlo = *(const bf16x8*)(slot + i * 2048 + 1024 + l * 16);
        acc[i][0] = MFMA16(whi, x0, acc[i][0], 0, 0, 0);
        acc[i][0] = MFMA16(wlo, x0, acc[i][0], 0, 0, 0);
        acc[i][1] = MFMA16(whi, x1, acc[i][1], 0, 0, 0);
        acc[i][1] = MFMA16(wlo, x1, acc[i][1], 0, 0, 0);
    }
}

// ---------------- bias + CELU + pack C-fragments to dwords (in registers) ----------
template <int MB>
__device__ __forceinline__ void pack_epi(const f32x4 (*acc)[2], const float* bb, int q,
                                         uint32_t (*pk)[2][2]) {
    const int fr = q * 4;
#pragma unroll
    for (int mb = 0; mb < MB; ++mb) {
        const float4 bl = *(const float4*)(bb + mb * 16 + fr);
        const float bv[4] = {bl.x, bl.y, bl.z, bl.w};
#pragma unroll
        for (int c = 0; c < 2; ++c) {
            const float o0 = celu_f(acc[mb][c][0] + bv[0]);
            const float o1 = celu_f(acc[mb][c][1] + bv[1]);
            const float o2 = celu_f(acc[mb][c][2] + bv[2]);
            const float o3 = celu_f(acc[mb][c][3] + bv[3]);
            pk[mb][c][0] = pack2(o0, o1);
            pk[mb][c][1] = pack2(o2, o3);
        }
    }
}

// ---------------- in-register C->B transpose across q-groups ----------------
// target lane (a,q), dword d: features 32kb+8q+{2d,2d+1} of its atom.
// source: lane (a, (2q+(d>>1))&3), pk[2kb + (q>=2)][c][d&1].  (verified: R6/R8/R12/R15/R16/R18)
__device__ __forceinline__ bf16x8 xchg(uint32_t pe0, uint32_t pe1,
                                       uint32_t po0, uint32_t po1, int a, int q) {
    union { uint32_t u[4]; bf16x8 v; } r;
#pragma unroll
    for (int d = 0; d < 4; ++d) {
        const int src = a + 16 * ((2 * q + (d >> 1)) & 3);
        const uint32_t ve = __shfl((d & 1) ? pe1 : pe0, src);
        const uint32_t vo = __shfl((d & 1) ? po1 : po0, src);
        r.u[d] = (q >= 2) ? vo : ve;
    }
    return r.v;
}

// ---------------- pass 2: fused MFMA MLP; the verified optimum (R16/R18) ----------
// 4 waves x 32 atoms = 128-atom tiles; half-kb 42-step staging; __syncthreads
// steps; __launch_bounds__(256,3) -> VGPR 84 (at cap, no spill), 20.5KB LDS,
// ~2.3 blocks/CU. Verified: 163.5us (R16), 163.6us (R18). BODY FROZEN.
// Plateau model: wall = blocks x 43 steps x ~1.7k cyc / 256 CUs; step-bound,
// not BW-bound (L3-resident replays identical). Deeper pipelining structures
// all fail nondeterministically on this toolchain (see constraints above).
__global__ __launch_bounds__(256, 3) void mlp_mfma_kernel(
    const float* __restrict__ aev, const int* __restrict__ bidx,
    const int* __restrict__ counts, const int* __restrict__ tbase, int N,
    const __hip_bfloat16* __restrict__ wsw1, const float* __restrict__ b1,
    const __hip_bfloat16* __restrict__ wsw2, const float* __restrict__ b2,
    const __hip_bfloat16* __restrict__ wsw3, const float* __restrict__ b3,
    const float* __restrict__ W4, const float* __restrict__ b4,
    float* __restrict__ partials) {
    __shared__ __align__(16) char Wslot[2][10240];
    const int b = blockIdx.x, t = threadIdx.x;
    const int tb1 = tbase[1], tb2 = tbase[2], tb3 = tbase[3], tb4 = tbase[4];
    if (b >= tb4) return;               // block-uniform, before any barrier
    const int e = (b >= tb1) + (b >= tb2) + (b >= tb3);
    const int tile = b - (e == 0 ? 0 : e == 1 ? tb1 : e == 2 ? tb2 : tb3);
    const int cnt = counts[e];
    const int w = t >> 6, l = t & 63;
    const int wbase = tile * 128 + w * 32;
    const int a = l & 15, q = l >> 4;
    const int g0 = wbase + a, g1 = wbase + 16 + a;
    const bool v0g = g0 < cnt, v1g = g1 < cnt;
    // tail waves run masked dummy work on row cnt-1: no wave-level exit.
    const int i0 = bidx[e * N + min(g0, cnt - 1)];
    const int i1 = bidx[e * N + min(g1, cnt - 1)];
    const float* row0 = aev + (size_t)i0 * 384 + q * 8;
    const float* row1 = aev + (size_t)i1 * 384 + q * 8;

    const char* w1b = (const char*)wsw1;
    const char* w2b = (const char*)wsw2;
    const char* w3b = (const char*)wsw3;

    // prologue: stage step 0, preload X kb=0
    float4 na = *(const float4*)(row0);
    float4 nb = *(const float4*)(row0 + 4);
    float4 nc = *(const float4*)(row1);
    float4 nd = *(const float4*)(row1 + 4);
    stage_for(0, e, w, l, w1b, w2b, w3b, &Wslot[0][0]);
    __syncthreads();

    int step = 0;

    // ---- layer 1: X[32x384] -> 160
    f32x4 acc1[10][2] = {};
#pragma unroll 1
    for (int kb = 0; kb < 12; ++kb) {
        const bf16x8 x0 = cvt8(na, nb), x1 = cvt8(nc, nd);
        stage_for(step + 1, e, w, l, w1b, w2b, w3b, &Wslot[(step + 1) & 1][0]);
        consume_slot<5>(&Wslot[step & 1][0], l, x0, x1, &acc1[0]);
        __syncthreads(); ++step;
        if (kb < 11) {                  // named-reg 1-step X prefetch
            na = *(const float4*)(row0 + (kb + 1) * 32);
            nb = *(const float4*)(row0 + (kb + 1) * 32 + 4);
            nc = *(const float4*)(row1 + (kb + 1) * 32);
            nd = *(const float4*)(row1 + (kb + 1) * 32 + 4);
        }
        stage_for(step + 1, e, w, l, w1b, w2b, w3b, &Wslot[(step + 1) & 1][0]);
        consume_slot<5>(&Wslot[step & 1][0], l, x0, x1, &acc1[5]);
        __syncthreads(); ++step;
    }

    // ---- layer 1 -> 2 interface: pack + shuffle transpose (no LDS)
    uint32_t pk1[10][2][2];
    pack_epi<10>(acc1, b1 + e * 160, q, pk1);

    // ---- layer 2: 160 -> 128 (steps 24..33, fully unrolled: static pk indices)
    f32x4 acc2[8][2] = {};
#pragma unroll
    for (int kb2 = 0; kb2 < 5; ++kb2) {
        const bf16x8 h0 = xchg(pk1[2 * kb2][0][0], pk1[2 * kb2][0][1],
                               pk1[2 * kb2 + 1][0][0], pk1[2 * kb2 + 1][0][1], a, q);
        const bf16x8 h1 = xchg(pk1[2 * kb2][1][0], pk1[2 * kb2][1][1],
                               pk1[2 * kb2 + 1][1][0], pk1[2 * kb2 + 1][1][1], a, q);
        const int s0 = 24 + 2 * kb2;
        stage_for(s0 + 1, e, w, l, w1b, w2b, w3b, &Wslot[(s0 + 1) & 1][0]);
        consume_slot<4>(&Wslot[s0 & 1][0], l, h0, h1, &acc2[0]);
        __syncthreads();
        stage_for(s0 + 2, e, w, l, w1b, w2b, w3b, &Wslot[(s0 + 2) & 1][0]);
        consume_slot<4>(&Wslot[(s0 + 1) & 1][0], l, h0, h1, &acc2[4]);
        __syncthreads();
    }

    // ---- layer 2 -> 3 interface
    uint32_t pk2[8][2][2];
    pack_epi<8>(acc2, b2 + e * 128, q, pk2);

    // ---- layer 3: 128 -> 96 (steps 34..41, fully unrolled)
    f32x4 acc3[6][2] = {};
#pragma unroll
    for (int kb3 = 0; kb3 < 4; ++kb3) {
        const bf16x8 h0 = xchg(pk2[2 * kb3][0][0], pk2[2 * kb3][0][1],
                               pk2[2 * kb3 + 1][0][0], pk2[2 * kb3 + 1][0][1], a, q);
        const bf16x8 h1 = xchg(pk2[2 * kb3][1][0], pk2[2 * kb3][1][1],
                               pk2[2 * kb3 + 1][1][0], pk2[2 * kb3 + 1][1][1], a, q);
        const int s0 = 34 + 2 * kb3;
        stage_for(s0 + 1, e, w, l, w1b, w2b, w3b, &Wslot[(s0 + 1) & 1][0]);
        consume_slot<3>(&Wslot[s0 & 1][0], l, h0, h1, &acc3[0]);
        __syncthreads();
        stage_for(s0 + 2, e, w, l, w1b, w2b, w3b, &Wslot[(s0 + 2) & 1][0]);  // 42 = no-op at end
        consume_slot<3>(&Wslot[(s0 + 1) & 1][0], l, h0, h1, &acc3[3]);
        __syncthreads();
    }

    // ---- layer 3 epilogue fused with layer 4 (96 -> 1) dot
    const int fr = q * 4;
    float en0 = 0.f, en1 = 0.f;
#pragma unroll
    for (int mb = 0; mb < 6; ++mb) {
        const float4 bl = *(const float4*)(b3 + e * 96 + mb * 16 + fr);
        const float4 wv = *(const float4*)(W4 + e * 96 + mb * 16 + fr);
        const float bv[4] = {bl.x, bl.y, bl.z, bl.w};
        const float wb[4] = {wv.x, wv.y, wv.z, wv.w};
#pragma unroll
        for (int r = 0; r < 4; ++r) {
            en0 += celu_f(acc3[mb][0][r] + bv[r]) * wb[r];
            en1 += celu_f(acc3[mb][1][r] + bv[r]) * wb[r];
        }
    }
    en0 += __shfl_xor(en0, 16); en0 += __shfl_xor(en0, 32);
    en1 += __shfl_xor(en1, 16); en1 += __shfl_xor(en1, 32);
    const float b4e = b4[e];
    float p = 0.f;
    if (l < 16) p = (v0g ? en0 + b4e : 0.f) + (v1g ? en1 + b4e : 0.f);
#pragma unroll
    for (int off = 1; off <= 32; off <<= 1) p += __shfl_xor(p, off);
    if (l == 0) partials[b * 4 + w] = p;
}

// ---------------- pass 3: deterministic tree reduce (1024 threads, 16 waves) -----
__global__ void reduce_kernel(const float* __restrict__ partials,
                              const int* __restrict__ tbase, float* __restrict__ out) {
    __shared__ float wsum[16];
    const int n = tbase[4] * 4;
    const int t = threadIdx.x;
    float s = 0.f;
    for (int i = t; i < n; i += 1024) s += partials[i];
#pragma unroll
    for (int off = 32; off; off >>= 1) s += __shfl_down(s, off);
    if ((t & 63) == 0) wsum[t >> 6] = s;
    __syncthreads();
    if (t == 0) {
        float tot = 0.f;
        for (int ww = 0; ww < 16; ++ww) tot += wsum[ww];
        out[0] = tot;
    }
}

extern "C" void kernel_launch(void* const* d_in, const int* in_sizes, int n_in,
                              void* d_out, int out_size, void* d_ws, size_t ws_size,
                              hipStream_t stream) {
    const float* aev     = (const float*)d_in[0];
    const int*   species = (const int*)d_in[1];
    const float* W1 = (const float*)d_in[2];
    const float* b1 = (const float*)d_in[3];
    const float* W2 = (const float*)d_in[4];
    const float* b2 = (const float*)d_in[5];
    const float* W3 = (const float*)d_in[6];
    const float* b3 = (const float*)d_in[7];
    const float* W4 = (const float*)d_in[8];
    const float* b4 = (const float*)d_in[9];
    float* out = (float*)d_out;

    const int N = in_sizes[1];
    const int gridx_max = (N + 127) / 128 + 4;   // >= sum_e ceil(cnt_e/128)

    // ws layout (256-aligned regions): counts[4] @0, tbase[5] @16, partials @256
    char* ws = (char*)d_ws;
    int* counts = (int*)ws;
    int* tbase  = (int*)(ws + 16);
    float* partials = (float*)(ws + 256);
    size_t off = 256 + (size_t)gridx_max * 4 * sizeof(float);
    off = (off + 255) & ~(size_t)255;
    __hip_bfloat16* wsw1 = (__hip_bfloat16*)(ws + off); off += (size_t)4 * 384 * 160 * 2 * 2;
    __hip_bfloat16* wsw2 = (__hip_bfloat16*)(ws + off); off += (size_t)4 * 160 * 128 * 2 * 2;
    __hip_bfloat16* wsw3 = (__hip_bfloat16*)(ws + off); off += (size_t)4 * 128 * 96 * 2 * 2;
    int* bidx = (int*)(ws + off);

    // single prep dispatch: all 3 weight splits + counts zeroing.
    constexpr int PREP_TOTAL = 4 * (10 * 12 + 8 * 5 + 6 * 4) * 512;   // 376832
    prep_kernel<<<(PREP_TOTAL + 255) / 256, 256, 0, stream>>>(W1, W2, W3,
                                                              wsw1, wsw2, wsw3, counts);

    bucket_kernel<<<(N + 255) / 256, 256, 0, stream>>>(species, N, counts, bidx);
    sched_kernel<<<1, 64, 0, stream>>>(counts, tbase);

    mlp_mfma_kernel<<<gridx_max, 256, 0, stream>>>(aev, bidx, counts, tbase, N,
                                                   wsw1, b1, wsw2, b2, wsw3, b3, W4, b4,
                                                   partials);

    reduce_kernel<<<1, 1024, 0, stream>>>(partials, tbase, out);
}